// Round 2
// baseline (33.158 us; speedup 1.0000x reference)
//
#include <hip/hip_runtime.h>
#include <math.h>

#define N_  4
#define C_  3
#define H_  540
#define W_  960
#define HO_ 1080
#define WO_ 1920

// Thread = (n, c, ly, tx): owns low-res cols [4tx, 4tx+4), output rows {2ly, 2ly+1},
// output cols [8tx, 8tx+8)  -> 16 output px, 4 float4 stores.
// All data needed (3x3 pools, bilinear taps, z-lattice, beta-lattice) lives in the
// 3-row x 6-col clamped window around (ly, 4tx..4tx+3):
//   ix(ox) = ox/2 + 0.25 - jx  -> x0 in {m-1, m}, m = ox>>1  (within window)
//   iy(oy) = oy/2 + 0.25 - jy  -> y0 in {ly-1, ly}
//   z row = ly always (zy = 2ly + ry - jny even only when ry == jny)
// Border handling: window rows/cols are CLAMPED loads; for the 3x3 pool a clamped
// duplicate equals an in-window valid element, so plain min/max over the clamped
// window == reference's border-excluded pool. Bilinear's index clamp likewise
// resolves to the same clamped window values. No +/-INFINITY needed.
__global__ __launch_bounds__(256) void taa_fused_kernel(
    const float* __restrict__ frame,
    const float* __restrict__ jitter,
    float* __restrict__ out,
    int total_threads, long long out_elems)
{
    const int TX = W_ / 4;   // 240
    int idx = blockIdx.x * blockDim.x + threadIdx.x;
    if (idx >= total_threads) return;

    int tx  = idx % TX;
    int t   = idx / TX;
    int ly  = t % H_;
    int nc  = t / H_;            // n*C_ + c  in [0,12)
    int n   = nc / C_;
    int lx0 = tx * 4;

    float jx = jitter[2 * n + 0];
    float jy = jitter[2 * n + 1];
    int jnx = (int)floorf(jx * 2.0f);
    int jny = (int)floorf(jy * 2.0f);
    int bjx = (int)floorf(jitter[0] * 2.0f);   // beta lattice uses batch-0 jitter
    int bjy = (int)floorf(jitter[1] * 2.0f);
    bool zcoin = (jnx == bjx) && (jny == bjy); // z-lattice coincides with beta-lattice

    const float* fp = frame + (size_t)nc * (H_ * W_);

    int r0 = (ly > 0)          ? ly - 1   : 0;
    int r2 = (ly < H_ - 1)     ? ly + 1   : H_ - 1;
    int cL = (lx0 > 0)         ? lx0 - 1  : 0;
    int cR = (lx0 + 4 < W_)    ? lx0 + 4  : W_ - 1;

    // ---- 3x6 clamped window (9 load instructions)
    float w0[6], w1[6], w2[6];
    {
        const float* rp = fp + r0 * W_;
        float4 m = *(const float4*)(rp + lx0);
        w0[0]=rp[cL]; w0[1]=m.x; w0[2]=m.y; w0[3]=m.z; w0[4]=m.w; w0[5]=rp[cR];
        rp = fp + ly * W_;
        m = *(const float4*)(rp + lx0);
        w1[0]=rp[cL]; w1[1]=m.x; w1[2]=m.y; w1[3]=m.z; w1[4]=m.w; w1[5]=rp[cR];
        rp = fp + r2 * W_;
        m = *(const float4*)(rp + lx0);
        w2[0]=rp[cL]; w2[1]=m.x; w2[2]=m.y; w2[3]=m.z; w2[4]=m.w; w2[5]=rp[cR];
    }

    // ---- 3x3 min/max pools for the 4 low-res cols (column partials first)
    float cmax[6], cmin[6];
    #pragma unroll
    for (int j = 0; j < 6; ++j) {
        cmax[j] = fmaxf(fmaxf(w0[j], w1[j]), w2[j]);
        cmin[j] = fminf(fminf(w0[j], w1[j]), w2[j]);
    }
    float vmax[4], vmin[4];
    #pragma unroll
    for (int p = 0; p < 4; ++p) {
        vmax[p] = fmaxf(fmaxf(cmax[p], cmax[p+1]), cmax[p+2]);
        vmin[p] = fminf(fminf(cmin[p], cmin[p+1]), cmin[p+2]);
    }

    // ---- x-grid constants per output-column parity (exact reference op order)
    float wx_[2]; bool dxm1_[2];
    #pragma unroll
    for (int par = 0; par < 2; ++par) {
        int ox = 8 * tx + par;
        float xs = (2.0f * (float)ox + 1.0f) / (float)WO_ - 1.0f;
        float gx = xs + 2.0f * (0.5f - jx) / (float)W_;
        float ix = ((gx + 1.0f) * (float)W_ - 1.0f) / 2.0f;
        float x0f = floorf(ix);
        wx_[par]   = ix - x0f;
        dxm1_[par] = ((int)x0f < 4 * tx);   // x0 = m-1 (window shift) vs m
    }

    float res[2][8];
    #pragma unroll
    for (int ry = 0; ry < 2; ++ry) {
        int oy = 2 * ly + ry;
        float ysv = (2.0f * (float)oy + 1.0f) / (float)HO_ - 1.0f;
        float gy = ysv + 2.0f * (0.5f - jy) / (float)H_;
        float iy = ((gy + 1.0f) * (float)H_ - 1.0f) / 2.0f;
        float y0f = floorf(iy);
        float wy  = iy - y0f;
        bool up = ((int)y0f < ly);   // y0 row = ly-1 (window row0) else ly (row1)

        float a0[6], a1[6];          // dy-resolved top/bottom rows (static idx)
        #pragma unroll
        for (int j = 0; j < 6; ++j) {
            a0[j] = up ? w0[j] : w1[j];
            a1[j] = up ? w1[j] : w2[j];
        }

        #pragma unroll
        for (int rx = 0; rx < 8; ++rx) {
            int par = rx & 1;
            int b   = rx >> 1;                 // static: pool col / z col / tap base
            float wx = wx_[par];
            bool  dm = dxm1_[par];
            float v00 = dm ? a0[b]   : a0[b+1];
            float v01 = dm ? a0[b+1] : a0[b+2];
            float v10 = dm ? a1[b]   : a1[b+1];
            float v11 = dm ? a1[b+1] : a1[b+2];
            float top = v00 + wx * (v01 - v00);
            float bot = v10 + wx * (v11 - v10);
            float bil = top + wy * (bot - top);
            float h = fminf(vmax[b], bil);
            h = fmaxf(vmin[b], h);
            // out = hist everywhere except beta-lattice px:
            //   out = 0.1*z + 0.9*hist, z = frame(ly, 4tx+b) iff z-lattice coincides
            bool isb = (ry == bjy) && (par == bjx);
            float zv = zcoin ? w1[b + 1] : 0.0f;
            res[ry][rx] = isb ? (0.1f * zv + (1.0f - 0.1f) * h) : h;
        }
    }

    size_t base = (size_t)nc * ((size_t)HO_ * WO_);
    #pragma unroll
    for (int ry = 0; ry < 2; ++ry) {
        size_t off = base + (size_t)(2 * ly + ry) * WO_ + (size_t)8 * tx;
        if ((long long)(off + 8) <= out_elems) {   // defensive: never write OOB
            *(float4*)(out + off)     = make_float4(res[ry][0], res[ry][1], res[ry][2], res[ry][3]);
            *(float4*)(out + off + 4) = make_float4(res[ry][4], res[ry][5], res[ry][6], res[ry][7]);
        }
    }
}

extern "C" void kernel_launch(void* const* d_in, const int* in_sizes, int n_in,
                              void* d_out, int out_size, void* d_ws, size_t ws_size,
                              hipStream_t stream) {
    const float* frame  = (const float*)d_in[0];
    const float* jitter = (const float*)d_in[1];
    float* out = (float*)d_out;

    const int total = N_ * C_ * H_ * (W_ / 4);   // 1,555,200 threads, 16 px each
    const int block = 256;
    const int grid  = (total + block - 1) / block;  // 6075 blocks exactly
    taa_fused_kernel<<<grid, block, 0, stream>>>(frame, jitter, out,
                                                 total, (long long)out_size);
}

// Round 3
// 30.041 us; speedup vs baseline: 1.1038x; 1.1038x over previous
//
#include <hip/hip_runtime.h>
#include <math.h>

#define N_  4
#define C_  3
#define H_  540
#define W_  960
#define HO_ 1080
#define WO_ 1920

// Thread = (n, c, ly, tx): owns low-res cols [4tx, 4tx+4), output rows {2ly, 2ly+1},
// output cols [8tx, 8tx+8)  -> 16 output px, 4 float4 stores.
// Window proof: ix(ox) = ox/2 + 0.25 - jx -> x0 in {m-1, m}, m = ox>>1;
//               iy(oy) = oy/2 + 0.25 - jy -> y0 in {ly-1, ly}; z row == ly.
// Clamped window loads make border-excluded 3x3 pools == plain min/max over the
// clamped 3x6 window (duplicates never change min/max).
//
// R3 change: bijective chunked XCD swizzle (T1, m204). HW round-robins
// blockIdx.x%8 across XCDs; linear mapping puts adjacent rows on different
// XCDs -> 3x HBM re-fetch of frame rows. Chunked mapping gives each XCD a
// contiguous row band; the ly+/-1 re-reads then hit its private L2.
__global__ __launch_bounds__(256) void taa_fused_kernel(
    const float* __restrict__ frame,
    const float* __restrict__ jitter,
    float* __restrict__ out,
    int total_threads, int n_blocks, long long out_elems)
{
    // ---- bijective chunked XCD swizzle (nwg = n_blocks, 8 XCDs)
    int b   = blockIdx.x;
    int q   = n_blocks >> 3, r = n_blocks & 7;
    int xcd = b & 7, i = b >> 3;
    int wb  = (xcd < r ? xcd * (q + 1) : r * (q + 1) + (xcd - r) * q) + i;

    int idx = wb * 256 + threadIdx.x;
    if (idx >= total_threads) return;

    const int TX = W_ / 4;   // 240
    int tx  = idx % TX;
    int t   = idx / TX;
    int ly  = t % H_;
    int nc  = t / H_;            // n*C_ + c  in [0,12)
    int n   = nc / C_;
    int lx0 = tx * 4;

    float jx = jitter[2 * n + 0];
    float jy = jitter[2 * n + 1];
    int jnx = (int)floorf(jx * 2.0f);
    int jny = (int)floorf(jy * 2.0f);
    int bjx = (int)floorf(jitter[0] * 2.0f);   // beta lattice uses batch-0 jitter
    int bjy = (int)floorf(jitter[1] * 2.0f);
    bool zcoin = (jnx == bjx) && (jny == bjy); // z-lattice coincides with beta-lattice

    const float* fp = frame + (size_t)nc * (H_ * W_);

    int r0 = (ly > 0)          ? ly - 1   : 0;
    int r2 = (ly < H_ - 1)     ? ly + 1   : H_ - 1;
    int cL = (lx0 > 0)         ? lx0 - 1  : 0;
    int cR = (lx0 + 4 < W_)    ? lx0 + 4  : W_ - 1;

    // ---- 3x6 clamped window (9 load instructions)
    float w0[6], w1[6], w2[6];
    {
        const float* rp = fp + r0 * W_;
        float4 m = *(const float4*)(rp + lx0);
        w0[0]=rp[cL]; w0[1]=m.x; w0[2]=m.y; w0[3]=m.z; w0[4]=m.w; w0[5]=rp[cR];
        rp = fp + ly * W_;
        m = *(const float4*)(rp + lx0);
        w1[0]=rp[cL]; w1[1]=m.x; w1[2]=m.y; w1[3]=m.z; w1[4]=m.w; w1[5]=rp[cR];
        rp = fp + r2 * W_;
        m = *(const float4*)(rp + lx0);
        w2[0]=rp[cL]; w2[1]=m.x; w2[2]=m.y; w2[3]=m.z; w2[4]=m.w; w2[5]=rp[cR];
    }

    // ---- 3x3 min/max pools for the 4 low-res cols (column partials first)
    float cmax[6], cmin[6];
    #pragma unroll
    for (int j = 0; j < 6; ++j) {
        cmax[j] = fmaxf(fmaxf(w0[j], w1[j]), w2[j]);
        cmin[j] = fminf(fminf(w0[j], w1[j]), w2[j]);
    }
    float vmax[4], vmin[4];
    #pragma unroll
    for (int p = 0; p < 4; ++p) {
        vmax[p] = fmaxf(fmaxf(cmax[p], cmax[p+1]), cmax[p+2]);
        vmin[p] = fminf(fminf(cmin[p], cmin[p+1]), cmin[p+2]);
    }

    // ---- x-grid constants per output-column parity (exact reference op order)
    float wx_[2]; bool dxm1_[2];
    #pragma unroll
    for (int par = 0; par < 2; ++par) {
        int ox = 8 * tx + par;
        float xs = (2.0f * (float)ox + 1.0f) / (float)WO_ - 1.0f;
        float gx = xs + 2.0f * (0.5f - jx) / (float)W_;
        float ix = ((gx + 1.0f) * (float)W_ - 1.0f) / 2.0f;
        float x0f = floorf(ix);
        wx_[par]   = ix - x0f;
        dxm1_[par] = ((int)x0f < 4 * tx);   // x0 = m-1 (window shift) vs m
    }

    float res[2][8];
    #pragma unroll
    for (int ry = 0; ry < 2; ++ry) {
        int oy = 2 * ly + ry;
        float ysv = (2.0f * (float)oy + 1.0f) / (float)HO_ - 1.0f;
        float gy = ysv + 2.0f * (0.5f - jy) / (float)H_;
        float iy = ((gy + 1.0f) * (float)H_ - 1.0f) / 2.0f;
        float y0f = floorf(iy);
        float wy  = iy - y0f;
        bool up = ((int)y0f < ly);   // y0 row = ly-1 (window row0) else ly (row1)

        float a0[6], a1[6];          // dy-resolved top/bottom rows (static idx)
        #pragma unroll
        for (int j = 0; j < 6; ++j) {
            a0[j] = up ? w0[j] : w1[j];
            a1[j] = up ? w1[j] : w2[j];
        }

        #pragma unroll
        for (int rx = 0; rx < 8; ++rx) {
            int par = rx & 1;
            int bcol = rx >> 1;               // static: pool col / z col / tap base
            float wx = wx_[par];
            bool  dm = dxm1_[par];
            float v00 = dm ? a0[bcol]   : a0[bcol+1];
            float v01 = dm ? a0[bcol+1] : a0[bcol+2];
            float v10 = dm ? a1[bcol]   : a1[bcol+1];
            float v11 = dm ? a1[bcol+1] : a1[bcol+2];
            float top = v00 + wx * (v01 - v00);
            float bot = v10 + wx * (v11 - v10);
            float bil = top + wy * (bot - top);
            float h = fminf(vmax[bcol], bil);
            h = fmaxf(vmin[bcol], h);
            bool isb = (ry == bjy) && (par == bjx);
            float zv = zcoin ? w1[bcol + 1] : 0.0f;
            res[ry][rx] = isb ? (0.1f * zv + (1.0f - 0.1f) * h) : h;
        }
    }

    size_t base = (size_t)nc * ((size_t)HO_ * WO_);
    #pragma unroll
    for (int ry = 0; ry < 2; ++ry) {
        size_t off = base + (size_t)(2 * ly + ry) * WO_ + (size_t)8 * tx;
        if ((long long)(off + 8) <= out_elems) {   // defensive: never write OOB
            *(float4*)(out + off)     = make_float4(res[ry][0], res[ry][1], res[ry][2], res[ry][3]);
            *(float4*)(out + off + 4) = make_float4(res[ry][4], res[ry][5], res[ry][6], res[ry][7]);
        }
    }
}

extern "C" void kernel_launch(void* const* d_in, const int* in_sizes, int n_in,
                              void* d_out, int out_size, void* d_ws, size_t ws_size,
                              hipStream_t stream) {
    const float* frame  = (const float*)d_in[0];
    const float* jitter = (const float*)d_in[1];
    float* out = (float*)d_out;

    const int total = N_ * C_ * H_ * (W_ / 4);   // 1,555,200 threads, 16 px each
    const int block = 256;
    const int grid  = (total + block - 1) / block;  // 6075 blocks exactly
    taa_fused_kernel<<<grid, block, 0, stream>>>(frame, jitter, out,
                                                 total, grid, (long long)out_size);
}